// Round 8
// baseline (329.920 us; speedup 1.0000x reference)
//
#include <hip/hip_runtime.h>
#include <stdint.h>

// MS-SSIM + L1 fused loss, MI355X.
// R8: R7 with the weight-centering bug fixed. R7 computed the register
// weight fragments as exp(-t^2/2s^2) with t=k-n in [0,32]; the verified R6
// LDS construction is exp(-(t-16)^2/2s^2) (gaussian centered mid-band).
// One-line fix: d = t-16 in the exponent. All other R7 changes retained:
//  - weight frags in registers (build_wm + ~30 barriers deleted)
//  - bf16 pack via +0x8000 + v_perm
//  - |x-y| staged as 6th plane during staging
//  - next-channel global prefetch into registers
//  - disc^2 folded into fused kernel
// Barriers/block ~21. LDS: XQ 6*9.2KB + PT 23KB = 78.4KB -> 2 blk/CU.

#define TILE 32
#define HALO 16
#define SSTR 72            // bf16 stride (144B row, 16B-multiple)
#define PLN  (64 * SSTR)
#define PTPLN (32 * SSTR)
#define NT   256

#define C1c 1.0e-4f
#define C2c 9.0e-4f

typedef short bf16x8 __attribute__((ext_vector_type(8)));
typedef float f32x4  __attribute__((ext_vector_type(4)));
typedef unsigned short ush;

// ---- compile-time 1/sum of the 33-tap gaussian ----
constexpr double cexp(double xx) {
  if (xx < -700.0) return 0.0;
  const double ln2 = 0.6931471805599453, il2 = 1.4426950408889634;
  double kd = xx * il2;
  long long k = (long long)(kd + (kd >= 0 ? 0.5 : -0.5));
  double r = xx - (double)k * ln2;
  double t = 1.0, s = 1.0;
  for (int i = 1; i <= 22; ++i) { t *= r / (double)i; s += t; }
  double p = 1.0, base = (k >= 0) ? 2.0 : 0.5;
  long long n = (k >= 0) ? k : -k;
  while (n) { if (n & 1) p *= base; base *= base; n >>= 1; }
  return s * p;
}
constexpr float gsi(double sigma) {
  double inv = 1.0 / (2.0 * sigma * sigma);
  double s = 0.0;
  for (int k = -16; k <= 16; ++k) s += cexp(-(double)(k * k) * inv);
  return (float)(1.0 / s);
}
constexpr float SI05 = gsi(0.5), SI10 = gsi(1.0), SI20 = gsi(2.0),
                SI40 = gsi(4.0), SI80 = gsi(8.0);

// pack two f32 -> bf16x2 (round-half-up; tie bias ~2^-16 prob, 1 ulp)
__device__ __forceinline__ unsigned f2bf_pk(float lo, float hi) {
  union { float f; unsigned u; } a, b; a.f = lo; b.f = hi;
  return __builtin_amdgcn_perm(b.u + 0x8000u, a.u + 0x8000u, 0x07060302u);
}

// One separable conv pass via two banded GEMMs. NQ=5: planes {x,y,x2,y2,xy};
// NQ=1: plane q0. Weight frags built in regs; 2 barriers total.
template<int NQ>
__device__ __forceinline__ void conv_pass(float inv, float si,
    const ush* __restrict__ XQ, int q0,
    ush* __restrict__ PT, int wave, int lane, f32x4* V) {
  const int l16 = lane & 15, quad = lane >> 4;
  bf16x8 W[2][2];
  #pragma unroll
  for (int sb = 0; sb < 2; ++sb) {
    #pragma unroll
    for (int h = 0; h < 2; ++h) {
      unsigned pk[4];
      #pragma unroll
      for (int p = 0; p < 4; ++p) {
        float wv[2];
        #pragma unroll
        for (int e = 0; e < 2; ++e) {
          const int t = quad * 8 + p * 2 + e + 32 * h - 16 * sb - l16;
          const int d = t - 16;   // gaussian centered mid-band (R7 bug: used t)
          wv[e] = (t >= 0 && t <= 32) ? __expf(-(float)(d * d) * inv) * si : 0.f;
        }
        pk[p] = f2bf_pk(wv[0], wv[1]);
      }
      union { unsigned u[4]; bf16x8 v; } cv;
      cv.u[0] = pk[0]; cv.u[1] = pk[1]; cv.u[2] = pk[2]; cv.u[3] = pk[3];
      W[sb][h] = cv.v;
    }
  }
  __syncthreads();                       // XQ staged / prev PT readers done
  // H-GEMM: D(64x32) = XQ(64x64) x Wh; store transposed bf16 into PT
  const int m0 = wave * 16;
  #pragma unroll
  for (int q = 0; q < NQ; ++q) {
    const ush* xp = XQ + (q0 + q) * PLN + (m0 + l16) * SSTR + quad * 8;
    const bf16x8 a0 = *(const bf16x8*)xp;
    const bf16x8 a1 = *(const bf16x8*)(xp + 32);
    #pragma unroll
    for (int nt = 0; nt < 2; ++nt) {
      f32x4 acc = {0.f, 0.f, 0.f, 0.f};
      acc = __builtin_amdgcn_mfma_f32_16x16x32_bf16(a0, W[nt][0], acc, 0, 0, 0);
      acc = __builtin_amdgcn_mfma_f32_16x16x32_bf16(a1, W[nt][1], acc, 0, 0, 0);
      uint2 u;
      u.x = f2bf_pk(acc[0], acc[1]);
      u.y = f2bf_pk(acc[2], acc[3]);
      *(uint2*)(PT + q * PTPLN + (nt * 16 + l16) * SSTR + m0 + quad * 4) = u;
    }
  }
  __syncthreads();                       // PT complete
  // V-GEMM: D(32x32) = Wv(32x64) x P
  const int sv = wave >> 1, n0 = (wave & 1) * 16;
  #pragma unroll
  for (int q = 0; q < NQ; ++q) {
    const ush* pp = PT + q * PTPLN + (n0 + l16) * SSTR + quad * 8;
    const bf16x8 b0 = *(const bf16x8*)pp;
    const bf16x8 b1 = *(const bf16x8*)(pp + 32);
    f32x4 acc = {0.f, 0.f, 0.f, 0.f};
    acc = __builtin_amdgcn_mfma_f32_16x16x32_bf16(W[sv][0], b0, acc, 0, 0, 0);
    acc = __builtin_amdgcn_mfma_f32_16x16x32_bf16(W[sv][1], b1, acc, 0, 0, 0);
    V[q] = acc;
  }
}

__global__ __launch_bounds__(NT)
void msssim_fused_kernel(const float* __restrict__ x, const float* __restrict__ y,
                         const float* __restrict__ disc,
                         float* __restrict__ partials) {
  __shared__ ush XQ[6 * PLN];      // planes: x, y, x2, y2, xy, |x-y|
  __shared__ ush PT[5 * PTPLN];
  __shared__ float red[12];

  const int tid = threadIdx.x;
  const int wave = tid >> 6, lane = tid & 63;
  const int bx = blockIdx.x, by = blockIdx.y, b = blockIdx.z;
  const int x0 = bx * TILE - HALO, y0 = by * TILE - HALO;
  const int blk = (b * 16 + by) * 16 + bx;

  // disc^2 partial (16 elems/block), issued early so latency hides
  float d2 = 0.f;
  { const int di = blk * 16 + tid;
    if (tid < 16 && di < 8 * 62 * 62) { const float dd = disc[di] - 1.f; d2 = dd * dd; } }

  const int sr = tid >> 4;           // staging row within 16-row band
  const int sc = (tid & 15) * 4;     // staging col group

  float4 PX[4], PY[4];
  auto issue_loads = [&](int ch) {
    const float* __restrict__ xs = x + (size_t)(b * 3 + ch) * 262144;
    const float* __restrict__ ys = y + (size_t)(b * 3 + ch) * 262144;
    #pragma unroll
    for (int it = 0; it < 4; ++it) {
      const int r = it * 16 + sr;
      const int gy = y0 + r, gx = x0 + sc;
      const bool rowok = (gy >= 0) && (gy < 512);
      if (rowok && gx >= 0 && gx <= 508) {
        PX[it] = *(const float4*)(xs + gy * 512 + gx);
        PY[it] = *(const float4*)(ys + gy * 512 + gx);
      } else {
        float tx[4], ty[4];
        #pragma unroll
        for (int e = 0; e < 4; ++e) {
          const int g = gx + e;
          const bool ok = rowok && (g >= 0) && (g < 512);
          tx[e] = ok ? xs[gy * 512 + g] : 0.f;
          ty[e] = ok ? ys[gy * 512 + g] : 0.f;
        }
        PX[it] = make_float4(tx[0], tx[1], tx[2], tx[3]);
        PY[it] = make_float4(ty[0], ty[1], ty[2], ty[3]);
      }
    }
  };

  float PIcs[4] = {1.f, 1.f, 1.f, 1.f};
  float gl1[4]  = {0.f, 0.f, 0.f, 0.f};
  float absacc  = 0.f;

  issue_loads(0);
  for (int ch = 0; ch < 3; ++ch) {
    // ---- stage 6 planes from registers (no leading barrier needed:
    //      all XQ readers finished before the prior pass's mid-barrier) ----
    #pragma unroll
    for (int it = 0; it < 4; ++it) {
      const int r = it * 16 + sr;
      float xv[4] = {PX[it].x, PX[it].y, PX[it].z, PX[it].w};
      float yv[4] = {PY[it].x, PY[it].y, PY[it].z, PY[it].w};
      float q2[4], q3[4], q4[4], q5[4];
      #pragma unroll
      for (int e = 0; e < 4; ++e) {
        xv[e] = fmaf(xv[e], 0.5f, 0.5f);
        yv[e] = fmaf(yv[e], 0.5f, 0.5f);
        q2[e] = xv[e] * xv[e]; q3[e] = yv[e] * yv[e];
        q4[e] = xv[e] * yv[e]; q5[e] = fabsf(xv[e] - yv[e]);
      }
      if (r >= 16 && r < 48 && sc >= 16 && sc < 48) {
        #pragma unroll
        for (int e = 0; e < 4; ++e) absacc += q5[e];
      }
      const int off = r * SSTR + sc;
      *(uint2*)(XQ + 0 * PLN + off) = make_uint2(f2bf_pk(xv[0], xv[1]), f2bf_pk(xv[2], xv[3]));
      *(uint2*)(XQ + 1 * PLN + off) = make_uint2(f2bf_pk(yv[0], yv[1]), f2bf_pk(yv[2], yv[3]));
      *(uint2*)(XQ + 2 * PLN + off) = make_uint2(f2bf_pk(q2[0], q2[1]), f2bf_pk(q2[2], q2[3]));
      *(uint2*)(XQ + 3 * PLN + off) = make_uint2(f2bf_pk(q3[0], q3[1]), f2bf_pk(q3[2], q3[3]));
      *(uint2*)(XQ + 4 * PLN + off) = make_uint2(f2bf_pk(q4[0], q4[1]), f2bf_pk(q4[2], q4[3]));
      *(uint2*)(XQ + 5 * PLN + off) = make_uint2(f2bf_pk(q5[0], q5[1]), f2bf_pk(q5[2], q5[3]));
    }
    if (ch < 2) issue_loads(ch + 1);   // prefetch next channel during conv work

    // ---- SSIM sigma passes ----
    const int nsig = (ch == 1) ? 3 : 2;
    #pragma unroll 1
    for (int sidx = 0; sidx < nsig; ++sidx) {
      float inv, si; int mult; bool last = false;
      if (ch == 0)      { inv = sidx ? 0.5f : 2.0f; si = sidx ? SI10 : SI05;
                          mult = sidx ? 2 : 3; }
      else if (ch == 1) { inv = (sidx == 0) ? 0.5f : (sidx == 1 ? 0.125f : 0.03125f);
                          si  = (sidx == 0) ? SI10 : (sidx == 1 ? SI20 : SI40);
                          mult = (sidx == 1) ? 3 : 1; }
      else              { inv = sidx ? 0.0078125f : 0.03125f;
                          si  = sidx ? SI80 : SI40;
                          mult = sidx ? 3 : 2; last = (sidx == 1); }
      f32x4 V[5];
      conv_pass<5>(inv, si, XQ, 0, PT, wave, lane, V);
      #pragma unroll
      for (int r = 0; r < 4; ++r) {
        const float mux = V[0][r], muy = V[1][r];
        const float A = mux * muy;
        const float Bq = mux * mux + muy * muy;
        const float S = V[2][r] + V[3][r] - Bq;
        const float sxy = V[4][r] - A;
        const float cs = (2.f * sxy + C2c) * __builtin_amdgcn_rcpf(S + C2c);
        float p = cs;
        if (mult >= 2) p *= cs;
        if (mult >= 3) p *= cs;
        if (last) {
          const float l = (2.f * A + C1c) * __builtin_amdgcn_rcpf(Bq + C1c);
          p *= l * l * l;
        }
        PIcs[r] *= p;
      }
    }
    // ---- gaussian L1 (sigma=8) on plane 5 ----
    { f32x4 V1[1];
      conv_pass<1>(0.0078125f, SI80, XQ, 5, PT, wave, lane, V1);
      #pragma unroll
      for (int r = 0; r < 4; ++r) gl1[r] += V1[0][r]; }
  }

  float mixsum = 0.f;
  #pragma unroll
  for (int r = 0; r < 4; ++r) {
    const float ssim = 1.f - PIcs[r];
    mixsum += 200.f * (0.025f * ssim + 0.975f * (gl1[r] * (1.f / 3.f)));
  }

  #pragma unroll
  for (int off = 32; off > 0; off >>= 1) {
    mixsum += __shfl_down(mixsum, off);
    absacc += __shfl_down(absacc, off);
    d2     += __shfl_down(d2, off);
  }
  if (lane == 0) { red[wave] = mixsum; red[4 + wave] = absacc; red[8 + wave] = d2; }
  __syncthreads();
  if (tid == 0) {
    float m = 0.f, a = 0.f, d = 0.f;
    #pragma unroll
    for (int i = 0; i < 4; ++i) { m += red[i]; a += red[4 + i]; d += red[8 + i]; }
    partials[3 * blk + 0] = m;
    partials[3 * blk + 1] = a;
    partials[3 * blk + 2] = d;
  }
}

__global__ __launch_bounds__(512)
void msssim_final_kernel(const float* __restrict__ partials,
                         float* __restrict__ out) {
  __shared__ float red[24];
  const int tid = threadIdx.x;
  float m = 0.f, a = 0.f, d2 = 0.f;
  for (int j = tid; j < 2048; j += 512) {
    m  += partials[3 * j + 0];
    a  += partials[3 * j + 1];
    d2 += partials[3 * j + 2];
  }
  #pragma unroll
  for (int off = 32; off > 0; off >>= 1) {
    m  += __shfl_down(m, off);
    a  += __shfl_down(a, off);
    d2 += __shfl_down(d2, off);
  }
  const int wave = tid >> 6, lane = tid & 63;
  if (lane == 0) { red[wave] = m; red[8 + wave] = a; red[16 + wave] = d2; }
  __syncthreads();
  if (tid == 0) {
    float sm = 0.f, sa = 0.f, sd = 0.f;
    #pragma unroll
    for (int i = 0; i < 8; ++i) { sm += red[i]; sa += red[8 + i]; sd += red[16 + i]; }
    const float mix_mean  = sm / (8.f * 512.f * 512.f);
    const float abs_mean  = sa / (8.f * 3.f * 512.f * 512.f);
    const float disc_mean = sd / (8.f * 62.f * 62.f);
    out[0] = 0.5f * (mix_mean + 100.f * abs_mean + disc_mean);
  }
}

extern "C" void kernel_launch(void* const* d_in, const int* in_sizes, int n_in,
                              void* d_out, int out_size, void* d_ws, size_t ws_size,
                              hipStream_t stream) {
  const float* x    = (const float*)d_in[0];
  const float* y    = (const float*)d_in[1];
  const float* disc = (const float*)d_in[2];
  // d_in[3] = g_masks (unused: weights recomputed on device)
  float* partials = (float*)d_ws;   // 2048*3 floats, fully overwritten each call
  dim3 grid(16, 16, 8);
  msssim_fused_kernel<<<grid, NT, 0, stream>>>(x, y, disc, partials);
  msssim_final_kernel<<<1, 512, 0, stream>>>(partials, (float*)d_out);
}

// Round 9
// 177.821 us; speedup vs baseline: 1.8553x; 1.8553x over previous
//
#include <hip/hip_runtime.h>
#include <stdint.h>

// MS-SSIM + L1 fused loss, MI355X.
// R9: bisect of the R6->R8 regression (138 -> 267us). R8's only hot-path
// delta vs R6 was the per-pass register-resident weight build (32 __expf
// chains feeding MFMA operands). Revert weights to R6's verified LDS WM
// (streamlined: constexpr 1/sum kills the serial-sum + one barrier),
// KEEP R8's independent wins: next-channel register prefetch, disc^2 fold,
// rcpf epilogue, v_perm bf16 pack. XQ back to 5 planes + |x-y| rewrite
// (LDS ~74KB -> 2 blocks/CU).

#define TILE 32
#define HALO 16
#define SSTR 72            // bf16 stride (144B row, 16B-multiple)
#define PLN  (64 * SSTR)
#define PTPLN (32 * SSTR)
#define NT   256

#define C1c 1.0e-4f
#define C2c 9.0e-4f

typedef short bf16x8 __attribute__((ext_vector_type(8)));
typedef float f32x4  __attribute__((ext_vector_type(4)));
typedef unsigned short ush;

// ---- compile-time 1/sum of the 33-tap gaussian ----
constexpr double cexp(double xx) {
  if (xx < -700.0) return 0.0;
  const double ln2 = 0.6931471805599453, il2 = 1.4426950408889634;
  double kd = xx * il2;
  long long k = (long long)(kd + (kd >= 0 ? 0.5 : -0.5));
  double r = xx - (double)k * ln2;
  double t = 1.0, s = 1.0;
  for (int i = 1; i <= 22; ++i) { t *= r / (double)i; s += t; }
  double p = 1.0, base = (k >= 0) ? 2.0 : 0.5;
  long long n = (k >= 0) ? k : -k;
  while (n) { if (n & 1) p *= base; base *= base; n >>= 1; }
  return s * p;
}
constexpr float gsi(double sigma) {
  double inv = 1.0 / (2.0 * sigma * sigma);
  double s = 0.0;
  for (int k = -16; k <= 16; ++k) s += cexp(-(double)(k * k) * inv);
  return (float)(1.0 / s);
}
constexpr float SI05 = gsi(0.5), SI10 = gsi(1.0), SI20 = gsi(2.0),
                SI40 = gsi(4.0), SI80 = gsi(8.0);

// pack two f32 -> bf16x2 (round-half-up; tie bias ~2^-16 prob, 1 ulp)
__device__ __forceinline__ unsigned f2bf_pk(float lo, float hi) {
  union { float f; unsigned u; } a, b; a.f = lo; b.f = hi;
  return __builtin_amdgcn_perm(b.u + 0x8000u, a.u + 0x8000u, 0x07060302u);
}
__device__ __forceinline__ ush f2bf1(float f) {
  union { float f; unsigned u; } c; c.f = f;
  return (ush)((c.u + 0x8000u) >> 16);
}
__device__ __forceinline__ float bf2f_lo(unsigned u) {
  union { unsigned u; float f; } c; c.u = u << 16; return c.f;
}
__device__ __forceinline__ float bf2f_hi(unsigned u) {
  union { unsigned u; float f; } c; c.u = u & 0xFFFF0000u; return c.f;
}

// Build WM[m][k] = wfull[k-m] (k-m in [0,32], gaussian centered at 16), bf16.
// 3 barriers (R6 had 4-5: constexpr si removes the serial-sum step).
__device__ __forceinline__ void build_wm(float inv, float si,
                                         ush* __restrict__ WM,
                                         float* __restrict__ wf, int tid) {
  __syncthreads();                 // prior WM/XQ readers done
  if (tid < 33) {
    const float d = (float)(tid - 16);
    wf[tid] = __expf(-d * d * inv) * si;
  }
  __syncthreads();
  #pragma unroll
  for (int i = 0; i < 8; ++i) {
    const int idx = i * 256 + tid;         // 0..2047
    const int m = idx >> 6, k = idx & 63;
    const int t = k - m;
    const int tc = t < 0 ? 0 : (t > 32 ? 32 : t);
    const float v = (t >= 0 && t <= 32) ? wf[tc] : 0.f;
    WM[m * SSTR + k] = f2bf1(v);
  }
  __syncthreads();                 // WM ready (also orders staged XQ for H-GEMM)
}

// One separable conv pass via two banded GEMMs, weights from LDS WM.
template<int NQ>
__device__ __forceinline__ void conv_pass(const ush* __restrict__ XQ, int q0,
                                          const ush* __restrict__ WM,
                                          ush* __restrict__ PT,
                                          int wave, int lane, f32x4* V) {
  const int l16 = lane & 15, quad = lane >> 4;
  const int m0 = wave * 16;
  // H-GEMM: D(64x32) = XQ(64x64) x Wh; store transposed bf16 into PT
  #pragma unroll
  for (int q = 0; q < NQ; ++q) {
    const ush* xp = XQ + (q0 + q) * PLN + (m0 + l16) * SSTR + quad * 8;
    const bf16x8 a0 = *(const bf16x8*)xp;
    const bf16x8 a1 = *(const bf16x8*)(xp + 32);
    #pragma unroll
    for (int nt = 0; nt < 2; ++nt) {
      const ush* wp = WM + (nt * 16 + l16) * SSTR + quad * 8;
      const bf16x8 b0 = *(const bf16x8*)wp;
      const bf16x8 b1 = *(const bf16x8*)(wp + 32);
      f32x4 acc = {0.f, 0.f, 0.f, 0.f};
      acc = __builtin_amdgcn_mfma_f32_16x16x32_bf16(a0, b0, acc, 0, 0, 0);
      acc = __builtin_amdgcn_mfma_f32_16x16x32_bf16(a1, b1, acc, 0, 0, 0);
      uint2 u;
      u.x = f2bf_pk(acc[0], acc[1]);
      u.y = f2bf_pk(acc[2], acc[3]);
      *(uint2*)(PT + q * PTPLN + (nt * 16 + l16) * SSTR + m0 + quad * 4) = u;
    }
  }
  __syncthreads();                 // PT complete
  // V-GEMM: D(32x32) = Wv(32x64) x P
  const int sv0 = (wave >> 1) * 16, n0 = (wave & 1) * 16;
  const ush* ap = WM + (sv0 + l16) * SSTR + quad * 8;
  const bf16x8 wa0 = *(const bf16x8*)ap;
  const bf16x8 wa1 = *(const bf16x8*)(ap + 32);
  #pragma unroll
  for (int q = 0; q < NQ; ++q) {
    const ush* pp = PT + q * PTPLN + (n0 + l16) * SSTR + quad * 8;
    const bf16x8 b0 = *(const bf16x8*)pp;
    const bf16x8 b1 = *(const bf16x8*)(pp + 32);
    f32x4 acc = {0.f, 0.f, 0.f, 0.f};
    acc = __builtin_amdgcn_mfma_f32_16x16x32_bf16(wa0, b0, acc, 0, 0, 0);
    acc = __builtin_amdgcn_mfma_f32_16x16x32_bf16(wa1, b1, acc, 0, 0, 0);
    V[q] = acc;
  }
}

__global__ __launch_bounds__(NT)
void msssim_fused_kernel(const float* __restrict__ x, const float* __restrict__ y,
                         const float* __restrict__ disc,
                         float* __restrict__ partials) {
  __shared__ ush XQ[5 * PLN];      // planes: x, y, x2, y2, xy (plane4 -> |x-y| for L1)
  __shared__ ush PT[5 * PTPLN];
  __shared__ ush WM[32 * SSTR];
  __shared__ float wf[34];
  __shared__ float red[12];

  const int tid = threadIdx.x;
  const int wave = tid >> 6, lane = tid & 63;
  const int bx = blockIdx.x, by = blockIdx.y, b = blockIdx.z;
  const int x0 = bx * TILE - HALO, y0 = by * TILE - HALO;
  const int blk = (b * 16 + by) * 16 + bx;

  // disc^2 partial (16 elems/block), issued early so latency hides
  float d2 = 0.f;
  { const int di = blk * 16 + tid;
    if (tid < 16 && di < 8 * 62 * 62) { const float dd = disc[di] - 1.f; d2 = dd * dd; } }

  const int sr = tid >> 4;           // staging row within 16-row band
  const int sc = (tid & 15) * 4;     // staging col group

  float4 PX[4], PY[4];
  auto issue_loads = [&](int ch) {
    const float* __restrict__ xs = x + (size_t)(b * 3 + ch) * 262144;
    const float* __restrict__ ys = y + (size_t)(b * 3 + ch) * 262144;
    #pragma unroll
    for (int it = 0; it < 4; ++it) {
      const int r = it * 16 + sr;
      const int gy = y0 + r, gx = x0 + sc;
      const bool rowok = (gy >= 0) && (gy < 512);
      if (rowok && gx >= 0 && gx <= 508) {
        PX[it] = *(const float4*)(xs + gy * 512 + gx);
        PY[it] = *(const float4*)(ys + gy * 512 + gx);
      } else {
        float tx[4], ty[4];
        #pragma unroll
        for (int e = 0; e < 4; ++e) {
          const int g = gx + e;
          const bool ok = rowok && (g >= 0) && (g < 512);
          tx[e] = ok ? xs[gy * 512 + g] : 0.f;
          ty[e] = ok ? ys[gy * 512 + g] : 0.f;
        }
        PX[it] = make_float4(tx[0], tx[1], tx[2], tx[3]);
        PY[it] = make_float4(ty[0], ty[1], ty[2], ty[3]);
      }
    }
  };

  float PIcs[4] = {1.f, 1.f, 1.f, 1.f};
  float gl1[4]  = {0.f, 0.f, 0.f, 0.f};
  float absacc  = 0.f;

  issue_loads(0);
  for (int ch = 0; ch < 3; ++ch) {
    // ---- stage 5 planes from registers (no leading barrier: prior pass's
    //      V-GEMM reads only PT/WM; XQ readers all pre-PT-barrier) ----
    #pragma unroll
    for (int it = 0; it < 4; ++it) {
      const int r = it * 16 + sr;
      float xv[4] = {PX[it].x, PX[it].y, PX[it].z, PX[it].w};
      float yv[4] = {PY[it].x, PY[it].y, PY[it].z, PY[it].w};
      float q2[4], q3[4], q4[4];
      #pragma unroll
      for (int e = 0; e < 4; ++e) {
        xv[e] = fmaf(xv[e], 0.5f, 0.5f);
        yv[e] = fmaf(yv[e], 0.5f, 0.5f);
        q2[e] = xv[e] * xv[e]; q3[e] = yv[e] * yv[e];
        q4[e] = xv[e] * yv[e];
      }
      if (r >= 16 && r < 48 && sc >= 16 && sc < 48) {
        #pragma unroll
        for (int e = 0; e < 4; ++e) absacc += fabsf(xv[e] - yv[e]);
      }
      const int off = r * SSTR + sc;
      *(uint2*)(XQ + 0 * PLN + off) = make_uint2(f2bf_pk(xv[0], xv[1]), f2bf_pk(xv[2], xv[3]));
      *(uint2*)(XQ + 1 * PLN + off) = make_uint2(f2bf_pk(yv[0], yv[1]), f2bf_pk(yv[2], yv[3]));
      *(uint2*)(XQ + 2 * PLN + off) = make_uint2(f2bf_pk(q2[0], q2[1]), f2bf_pk(q2[2], q2[3]));
      *(uint2*)(XQ + 3 * PLN + off) = make_uint2(f2bf_pk(q3[0], q3[1]), f2bf_pk(q3[2], q3[3]));
      *(uint2*)(XQ + 4 * PLN + off) = make_uint2(f2bf_pk(q4[0], q4[1]), f2bf_pk(q4[2], q4[3]));
    }
    if (ch < 2) issue_loads(ch + 1);   // prefetch next channel during conv work

    // ---- SSIM sigma passes ----
    const int nsig = (ch == 1) ? 3 : 2;
    #pragma unroll 1
    for (int sidx = 0; sidx < nsig; ++sidx) {
      float inv, si; int mult; bool last = false;
      if (ch == 0)      { inv = sidx ? 0.5f : 2.0f; si = sidx ? SI10 : SI05;
                          mult = sidx ? 2 : 3; }
      else if (ch == 1) { inv = (sidx == 0) ? 0.5f : (sidx == 1 ? 0.125f : 0.03125f);
                          si  = (sidx == 0) ? SI10 : (sidx == 1 ? SI20 : SI40);
                          mult = (sidx == 1) ? 3 : 1; }
      else              { inv = sidx ? 0.0078125f : 0.03125f;
                          si  = sidx ? SI80 : SI40;
                          mult = sidx ? 3 : 2; last = (sidx == 1); }
      build_wm(inv, si, WM, wf, tid);
      f32x4 V[5];
      conv_pass<5>(XQ, 0, WM, PT, wave, lane, V);
      #pragma unroll
      for (int r = 0; r < 4; ++r) {
        const float mux = V[0][r], muy = V[1][r];
        const float A = mux * muy;
        const float Bq = mux * mux + muy * muy;
        const float S = V[2][r] + V[3][r] - Bq;
        const float sxy = V[4][r] - A;
        const float cs = (2.f * sxy + C2c) * __builtin_amdgcn_rcpf(S + C2c);
        float p = cs;
        if (mult >= 2) p *= cs;
        if (mult >= 3) p *= cs;
        if (last) {
          const float l = (2.f * A + C1c) * __builtin_amdgcn_rcpf(Bq + C1c);
          p *= l * l * l;
        }
        PIcs[r] *= p;
      }
    }

    // ---- gaussian L1 (sigma=8): rewrite plane 4 with |x-y|, then conv ----
    build_wm(0.0078125f, SI80, WM, wf, tid);
    #pragma unroll
    for (int i = 0; i < 4; ++i) {
      const int idx = i * 256 + tid;            // 0..1023
      const int r = idx >> 4, c4 = (idx & 15) * 4;
      const int off = r * SSTR + c4;
      const uint2 ux = *(const uint2*)(XQ + 0 * PLN + off);
      const uint2 uy = *(const uint2*)(XQ + 1 * PLN + off);
      const float d0 = fabsf(bf2f_lo(ux.x) - bf2f_lo(uy.x));
      const float d1 = fabsf(bf2f_hi(ux.x) - bf2f_hi(uy.x));
      const float d2x = fabsf(bf2f_lo(ux.y) - bf2f_lo(uy.y));
      const float d3 = fabsf(bf2f_hi(ux.y) - bf2f_hi(uy.y));
      *(uint2*)(XQ + 4 * PLN + off) = make_uint2(f2bf_pk(d0, d1), f2bf_pk(d2x, d3));
    }
    __syncthreads();
    { f32x4 V1[1];
      conv_pass<1>(XQ, 4, WM, PT, wave, lane, V1);
      #pragma unroll
      for (int r = 0; r < 4; ++r) gl1[r] += V1[0][r]; }
  }

  float mixsum = 0.f;
  #pragma unroll
  for (int r = 0; r < 4; ++r) {
    const float ssim = 1.f - PIcs[r];
    mixsum += 200.f * (0.025f * ssim + 0.975f * (gl1[r] * (1.f / 3.f)));
  }

  #pragma unroll
  for (int off = 32; off > 0; off >>= 1) {
    mixsum += __shfl_down(mixsum, off);
    absacc += __shfl_down(absacc, off);
    d2     += __shfl_down(d2, off);
  }
  if (lane == 0) { red[wave] = mixsum; red[4 + wave] = absacc; red[8 + wave] = d2; }
  __syncthreads();
  if (tid == 0) {
    float m = 0.f, a = 0.f, d = 0.f;
    #pragma unroll
    for (int i = 0; i < 4; ++i) { m += red[i]; a += red[4 + i]; d += red[8 + i]; }
    partials[3 * blk + 0] = m;
    partials[3 * blk + 1] = a;
    partials[3 * blk + 2] = d;
  }
}

__global__ __launch_bounds__(512)
void msssim_final_kernel(const float* __restrict__ partials,
                         float* __restrict__ out) {
  __shared__ float red[24];
  const int tid = threadIdx.x;
  float m = 0.f, a = 0.f, d2 = 0.f;
  for (int j = tid; j < 2048; j += 512) {
    m  += partials[3 * j + 0];
    a  += partials[3 * j + 1];
    d2 += partials[3 * j + 2];
  }
  #pragma unroll
  for (int off = 32; off > 0; off >>= 1) {
    m  += __shfl_down(m, off);
    a  += __shfl_down(a, off);
    d2 += __shfl_down(d2, off);
  }
  const int wave = tid >> 6, lane = tid & 63;
  if (lane == 0) { red[wave] = m; red[8 + wave] = a; red[16 + wave] = d2; }
  __syncthreads();
  if (tid == 0) {
    float sm = 0.f, sa = 0.f, sd = 0.f;
    #pragma unroll
    for (int i = 0; i < 8; ++i) { sm += red[i]; sa += red[8 + i]; sd += red[16 + i]; }
    const float mix_mean  = sm / (8.f * 512.f * 512.f);
    const float abs_mean  = sa / (8.f * 3.f * 512.f * 512.f);
    const float disc_mean = sd / (8.f * 62.f * 62.f);
    out[0] = 0.5f * (mix_mean + 100.f * abs_mean + disc_mean);
  }
}

extern "C" void kernel_launch(void* const* d_in, const int* in_sizes, int n_in,
                              void* d_out, int out_size, void* d_ws, size_t ws_size,
                              hipStream_t stream) {
  const float* x    = (const float*)d_in[0];
  const float* y    = (const float*)d_in[1];
  const float* disc = (const float*)d_in[2];
  // d_in[3] = g_masks (unused: weights recomputed on device)
  float* partials = (float*)d_ws;   // 2048*3 floats, fully overwritten each call
  dim3 grid(16, 16, 8);
  msssim_fused_kernel<<<grid, NT, 0, stream>>>(x, y, disc, partials);
  msssim_final_kernel<<<1, 512, 0, stream>>>(partials, (float*)d_out);
}

// Round 10
// 148.398 us; speedup vs baseline: 2.2232x; 1.1983x over previous
//
#include <hip/hip_runtime.h>
#include <stdint.h>

// MS-SSIM + L1 fused loss, MI355X.
// R10: barrier reduction on the verified R9 structure (~44 -> ~24 barriers).
//  - wf5[5][*]: all 5 normalized gaussian tap tables built ONCE (one-time
//    __expf); per-pass build_wm is fill-only (2 barriers, was 3).
//  - WM shared across same-sigma consecutive passes (order: 0.5,1 | 1,2,4 |
//    4,8 | 8-L1): builds 10 -> 5.
//  - gaussian-L1 deferred via conv linearity: SAD accumulated in 16 regs
//    during staging, written to plane 4 once, ONE conv<1> (was 3); per-channel
//    rewrite loops deleted; absacc derived from central SAD regs.
// Keeps: R9 LDS-WM weights (R8 register-expf build regressed 2x), prefetch,
// disc^2 fold, rcpf, v_perm pack. LDS ~75KB -> 2 blocks/CU.

#define TILE 32
#define HALO 16
#define SSTR 72            // bf16 stride (144B row, 16B-multiple)
#define PLN  (64 * SSTR)
#define PTPLN (32 * SSTR)
#define NT   256

#define C1c 1.0e-4f
#define C2c 9.0e-4f

typedef short bf16x8 __attribute__((ext_vector_type(8)));
typedef float f32x4  __attribute__((ext_vector_type(4)));
typedef unsigned short ush;

// ---- compile-time 1/sum of the 33-tap gaussian ----
constexpr double cexp(double xx) {
  if (xx < -700.0) return 0.0;
  const double ln2 = 0.6931471805599453, il2 = 1.4426950408889634;
  double kd = xx * il2;
  long long k = (long long)(kd + (kd >= 0 ? 0.5 : -0.5));
  double r = xx - (double)k * ln2;
  double t = 1.0, s = 1.0;
  for (int i = 1; i <= 22; ++i) { t *= r / (double)i; s += t; }
  double p = 1.0, base = (k >= 0) ? 2.0 : 0.5;
  long long n = (k >= 0) ? k : -k;
  while (n) { if (n & 1) p *= base; base *= base; n >>= 1; }
  return s * p;
}
constexpr float gsi(double sigma) {
  double inv = 1.0 / (2.0 * sigma * sigma);
  double s = 0.0;
  for (int k = -16; k <= 16; ++k) s += cexp(-(double)(k * k) * inv);
  return (float)(1.0 / s);
}
constexpr float SI05 = gsi(0.5), SI10 = gsi(1.0), SI20 = gsi(2.0),
                SI40 = gsi(4.0), SI80 = gsi(8.0);

// pack two f32 -> bf16x2 (round-half-up)
__device__ __forceinline__ unsigned f2bf_pk(float lo, float hi) {
  union { float f; unsigned u; } a, b; a.f = lo; b.f = hi;
  return __builtin_amdgcn_perm(b.u + 0x8000u, a.u + 0x8000u, 0x07060302u);
}
__device__ __forceinline__ ush f2bf1(float f) {
  union { float f; unsigned u; } c; c.f = f;
  return (ush)((c.u + 0x8000u) >> 16);
}

// Fill WM[m][k] = wf5[SIG][k-m] (k-m in [0,32] else 0). 2 barriers.
template<int SIG>
__device__ __forceinline__ void build_wm(ush* __restrict__ WM,
                                         const float (*__restrict__ wf5)[40],
                                         int tid) {
  __syncthreads();                 // prior WM readers (and staged XQ) ordered
  #pragma unroll
  for (int i = 0; i < 8; ++i) {
    const int idx = i * 256 + tid;         // 0..2047
    const int m = idx >> 6, k = idx & 63;
    const int t = k - m;
    const int tc = t < 0 ? 0 : (t > 32 ? 32 : t);
    float v = wf5[SIG][tc];
    v = (t >= 0 && t <= 32) ? v : 0.f;
    WM[m * SSTR + k] = f2bf1(v);
  }
  __syncthreads();                 // WM ready
}

// One separable conv pass via two banded GEMMs, weights from LDS WM.
// Caller must ensure a barrier ordered XQ/WM/PT before entry.
template<int NQ>
__device__ __forceinline__ void conv_pass(const ush* __restrict__ XQ, int q0,
                                          const ush* __restrict__ WM,
                                          ush* __restrict__ PT,
                                          int wave, int lane, f32x4* V) {
  const int l16 = lane & 15, quad = lane >> 4;
  const int m0 = wave * 16;
  // H-GEMM: D(64x32) = XQ(64x64) x Wh; store transposed bf16 into PT
  #pragma unroll
  for (int q = 0; q < NQ; ++q) {
    const ush* xp = XQ + (q0 + q) * PLN + (m0 + l16) * SSTR + quad * 8;
    const bf16x8 a0 = *(const bf16x8*)xp;
    const bf16x8 a1 = *(const bf16x8*)(xp + 32);
    #pragma unroll
    for (int nt = 0; nt < 2; ++nt) {
      const ush* wp = WM + (nt * 16 + l16) * SSTR + quad * 8;
      const bf16x8 b0 = *(const bf16x8*)wp;
      const bf16x8 b1 = *(const bf16x8*)(wp + 32);
      f32x4 acc = {0.f, 0.f, 0.f, 0.f};
      acc = __builtin_amdgcn_mfma_f32_16x16x32_bf16(a0, b0, acc, 0, 0, 0);
      acc = __builtin_amdgcn_mfma_f32_16x16x32_bf16(a1, b1, acc, 0, 0, 0);
      uint2 u;
      u.x = f2bf_pk(acc[0], acc[1]);
      u.y = f2bf_pk(acc[2], acc[3]);
      *(uint2*)(PT + q * PTPLN + (nt * 16 + l16) * SSTR + m0 + quad * 4) = u;
    }
  }
  __syncthreads();                 // PT complete
  // V-GEMM: D(32x32) = Wv(32x64) x P
  const int sv0 = (wave >> 1) * 16, n0 = (wave & 1) * 16;
  const ush* ap = WM + (sv0 + l16) * SSTR + quad * 8;
  const bf16x8 wa0 = *(const bf16x8*)ap;
  const bf16x8 wa1 = *(const bf16x8*)(ap + 32);
  #pragma unroll
  for (int q = 0; q < NQ; ++q) {
    const ush* pp = PT + q * PTPLN + (n0 + l16) * SSTR + quad * 8;
    const bf16x8 b0 = *(const bf16x8*)pp;
    const bf16x8 b1 = *(const bf16x8*)(pp + 32);
    f32x4 acc = {0.f, 0.f, 0.f, 0.f};
    acc = __builtin_amdgcn_mfma_f32_16x16x32_bf16(wa0, b0, acc, 0, 0, 0);
    acc = __builtin_amdgcn_mfma_f32_16x16x32_bf16(wa1, b1, acc, 0, 0, 0);
    V[q] = acc;
  }
}

// SSIM epilogue on V[5]
__device__ __forceinline__ void ssim_fold(const f32x4* V, int mult, bool last,
                                          float* PIcs) {
  #pragma unroll
  for (int r = 0; r < 4; ++r) {
    const float mux = V[0][r], muy = V[1][r];
    const float A = mux * muy;
    const float Bq = mux * mux + muy * muy;
    const float S = V[2][r] + V[3][r] - Bq;
    const float sxy = V[4][r] - A;
    const float cs = (2.f * sxy + C2c) * __builtin_amdgcn_rcpf(S + C2c);
    float p = cs;
    if (mult >= 2) p *= cs;
    if (mult >= 3) p *= cs;
    if (last) {
      const float l = (2.f * A + C1c) * __builtin_amdgcn_rcpf(Bq + C1c);
      p *= l * l * l;
    }
    PIcs[r] *= p;
  }
}

__global__ __launch_bounds__(NT)
void msssim_fused_kernel(const float* __restrict__ x, const float* __restrict__ y,
                         const float* __restrict__ disc,
                         float* __restrict__ partials) {
  __shared__ ush XQ[5 * PLN];      // planes: x, y, x2, y2, xy (plane4 -> SAD at end)
  __shared__ ush PT[5 * PTPLN];
  __shared__ ush WM[32 * SSTR];
  __shared__ float wf5[5][40];
  __shared__ float red[12];

  const int tid = threadIdx.x;
  const int wave = tid >> 6, lane = tid & 63;
  const int bx = blockIdx.x, by = blockIdx.y, b = blockIdx.z;
  const int x0 = bx * TILE - HALO, y0 = by * TILE - HALO;
  const int blk = (b * 16 + by) * 16 + bx;

  // disc^2 partial (16 elems/block), issued early so latency hides
  float d2 = 0.f;
  { const int di = blk * 16 + tid;
    if (tid < 16 && di < 8 * 62 * 62) { const float dd = disc[di] - 1.f; d2 = dd * dd; } }

  // one-time tap tables (first build_wm's leading barrier orders readers)
  if (tid < 165) {
    const int sig = tid / 33;
    const int k = tid - sig * 33;
    const float d = (float)(k - 16);
    float inv, si;
    if (sig == 0)      { inv = 2.0f;       si = SI05; }
    else if (sig == 1) { inv = 0.5f;       si = SI10; }
    else if (sig == 2) { inv = 0.125f;     si = SI20; }
    else if (sig == 3) { inv = 0.03125f;   si = SI40; }
    else               { inv = 0.0078125f; si = SI80; }
    wf5[sig][k] = __expf(-d * d * inv) * si;
  }

  const int sr = tid >> 4;           // staging row within 16-row band
  const int sc = (tid & 15) * 4;     // staging col group

  float4 PX[4], PY[4];
  auto issue_loads = [&](int ch) {
    const float* __restrict__ xs = x + (size_t)(b * 3 + ch) * 262144;
    const float* __restrict__ ys = y + (size_t)(b * 3 + ch) * 262144;
    #pragma unroll
    for (int it = 0; it < 4; ++it) {
      const int r = it * 16 + sr;
      const int gy = y0 + r, gx = x0 + sc;
      const bool rowok = (gy >= 0) && (gy < 512);
      if (rowok && gx >= 0 && gx <= 508) {
        PX[it] = *(const float4*)(xs + gy * 512 + gx);
        PY[it] = *(const float4*)(ys + gy * 512 + gx);
      } else {
        float tx[4], ty[4];
        #pragma unroll
        for (int e = 0; e < 4; ++e) {
          const int g = gx + e;
          const bool ok = rowok && (g >= 0) && (g < 512);
          tx[e] = ok ? xs[gy * 512 + g] : 0.f;
          ty[e] = ok ? ys[gy * 512 + g] : 0.f;
        }
        PX[it] = make_float4(tx[0], tx[1], tx[2], tx[3]);
        PY[it] = make_float4(ty[0], ty[1], ty[2], ty[3]);
      }
    }
  };

  float PIcs[4] = {1.f, 1.f, 1.f, 1.f};
  float sad[4][4];                    // sum over channels of |x-y|, 16 px/thread
  #pragma unroll
  for (int it = 0; it < 4; ++it)
    #pragma unroll
    for (int e = 0; e < 4; ++e) sad[it][e] = 0.f;

  issue_loads(0);

  // ---- staging helper: 5 planes + SAD accumulation ----
  auto stage = [&]() {
    #pragma unroll
    for (int it = 0; it < 4; ++it) {
      const int r = it * 16 + sr;
      float xv[4] = {PX[it].x, PX[it].y, PX[it].z, PX[it].w};
      float yv[4] = {PY[it].x, PY[it].y, PY[it].z, PY[it].w};
      float q2[4], q3[4], q4[4];
      #pragma unroll
      for (int e = 0; e < 4; ++e) {
        xv[e] = fmaf(xv[e], 0.5f, 0.5f);
        yv[e] = fmaf(yv[e], 0.5f, 0.5f);
        q2[e] = xv[e] * xv[e]; q3[e] = yv[e] * yv[e];
        q4[e] = xv[e] * yv[e];
        sad[it][e] += fabsf(xv[e] - yv[e]);
      }
      const int off = r * SSTR + sc;
      *(uint2*)(XQ + 0 * PLN + off) = make_uint2(f2bf_pk(xv[0], xv[1]), f2bf_pk(xv[2], xv[3]));
      *(uint2*)(XQ + 1 * PLN + off) = make_uint2(f2bf_pk(yv[0], yv[1]), f2bf_pk(yv[2], yv[3]));
      *(uint2*)(XQ + 2 * PLN + off) = make_uint2(f2bf_pk(q2[0], q2[1]), f2bf_pk(q2[2], q2[3]));
      *(uint2*)(XQ + 3 * PLN + off) = make_uint2(f2bf_pk(q3[0], q3[1]), f2bf_pk(q3[2], q3[3]));
      *(uint2*)(XQ + 4 * PLN + off) = make_uint2(f2bf_pk(q4[0], q4[1]), f2bf_pk(q4[2], q4[3]));
    }
  };

  f32x4 V[5];

  // ======== ch0: sigma 0.5 (x3), sigma 1 (x2) ========
  stage();
  issue_loads(1);
  build_wm<0>(WM, wf5, tid);                    // also orders staged XQ
  conv_pass<5>(XQ, 0, WM, PT, wave, lane, V);
  ssim_fold(V, 3, false, PIcs);
  build_wm<1>(WM, wf5, tid);
  conv_pass<5>(XQ, 0, WM, PT, wave, lane, V);
  ssim_fold(V, 2, false, PIcs);

  // ======== ch1: sigma 1 (x1, WM reused), sigma 2 (x3), sigma 4 (x1) ========
  stage();
  issue_loads(2);
  __syncthreads();                              // XQ staged (WM unchanged)
  conv_pass<5>(XQ, 0, WM, PT, wave, lane, V);
  ssim_fold(V, 1, false, PIcs);
  build_wm<2>(WM, wf5, tid);
  conv_pass<5>(XQ, 0, WM, PT, wave, lane, V);
  ssim_fold(V, 3, false, PIcs);
  build_wm<3>(WM, wf5, tid);
  conv_pass<5>(XQ, 0, WM, PT, wave, lane, V);
  ssim_fold(V, 1, false, PIcs);

  // ======== ch2: sigma 4 (x2, WM reused), sigma 8 (x3 + l^3) ========
  stage();
  __syncthreads();                              // XQ staged (WM unchanged)
  conv_pass<5>(XQ, 0, WM, PT, wave, lane, V);
  ssim_fold(V, 2, false, PIcs);
  build_wm<4>(WM, wf5, tid);
  conv_pass<5>(XQ, 0, WM, PT, wave, lane, V);
  ssim_fold(V, 3, true, PIcs);

  // ======== deferred gaussian L1: conv(SAD, sigma 8) (WM = sigma8 reused) ====
  #pragma unroll
  for (int it = 0; it < 4; ++it) {
    const int off = (it * 16 + sr) * SSTR + sc;
    *(uint2*)(XQ + 4 * PLN + off) =
        make_uint2(f2bf_pk(sad[it][0], sad[it][1]), f2bf_pk(sad[it][2], sad[it][3]));
  }
  __syncthreads();                              // SAD plane staged
  f32x4 V1[1];
  conv_pass<1>(XQ, 4, WM, PT, wave, lane, V1);

  // absacc = central sum of SAD regs (rows 16..47 are it=1,2; cols via sc)
  float absacc = 0.f;
  if (sc >= 16 && sc < 48) {
    #pragma unroll
    for (int it = 1; it <= 2; ++it)
      #pragma unroll
      for (int e = 0; e < 4; ++e) absacc += sad[it][e];
  }

  float mixsum = 0.f;
  #pragma unroll
  for (int r = 0; r < 4; ++r) {
    const float ssim = 1.f - PIcs[r];
    mixsum += 200.f * (0.025f * ssim + 0.975f * (V1[0][r] * (1.f / 3.f)));
  }

  #pragma unroll
  for (int off = 32; off > 0; off >>= 1) {
    mixsum += __shfl_down(mixsum, off);
    absacc += __shfl_down(absacc, off);
    d2     += __shfl_down(d2, off);
  }
  if (lane == 0) { red[wave] = mixsum; red[4 + wave] = absacc; red[8 + wave] = d2; }
  __syncthreads();
  if (tid == 0) {
    float m = 0.f, a = 0.f, d = 0.f;
    #pragma unroll
    for (int i = 0; i < 4; ++i) { m += red[i]; a += red[4 + i]; d += red[8 + i]; }
    partials[3 * blk + 0] = m;
    partials[3 * blk + 1] = a;
    partials[3 * blk + 2] = d;
  }
}

__global__ __launch_bounds__(512)
void msssim_final_kernel(const float* __restrict__ partials,
                         float* __restrict__ out) {
  __shared__ float red[24];
  const int tid = threadIdx.x;
  float m = 0.f, a = 0.f, d2 = 0.f;
  for (int j = tid; j < 2048; j += 512) {
    m  += partials[3 * j + 0];
    a  += partials[3 * j + 1];
    d2 += partials[3 * j + 2];
  }
  #pragma unroll
  for (int off = 32; off > 0; off >>= 1) {
    m  += __shfl_down(m, off);
    a  += __shfl_down(a, off);
    d2 += __shfl_down(d2, off);
  }
  const int wave = tid >> 6, lane = tid & 63;
  if (lane == 0) { red[wave] = m; red[8 + wave] = a; red[16 + wave] = d2; }
  __syncthreads();
  if (tid == 0) {
    float sm = 0.f, sa = 0.f, sd = 0.f;
    #pragma unroll
    for (int i = 0; i < 8; ++i) { sm += red[i]; sa += red[8 + i]; sd += red[16 + i]; }
    const float mix_mean  = sm / (8.f * 512.f * 512.f);
    const float abs_mean  = sa / (8.f * 3.f * 512.f * 512.f);
    const float disc_mean = sd / (8.f * 62.f * 62.f);
    out[0] = 0.5f * (mix_mean + 100.f * abs_mean + disc_mean);
  }
}

extern "C" void kernel_launch(void* const* d_in, const int* in_sizes, int n_in,
                              void* d_out, int out_size, void* d_ws, size_t ws_size,
                              hipStream_t stream) {
  const float* x    = (const float*)d_in[0];
  const float* y    = (const float*)d_in[1];
  const float* disc = (const float*)d_in[2];
  // d_in[3] = g_masks (unused: weights recomputed on device)
  float* partials = (float*)d_ws;   // 2048*3 floats, fully overwritten each call
  dim3 grid(16, 16, 8);
  msssim_fused_kernel<<<grid, NT, 0, stream>>>(x, y, disc, partials);
  msssim_final_kernel<<<1, 512, 0, stream>>>(partials, (float*)d_out);
}

// Round 11
// 146.934 us; speedup vs baseline: 2.2454x; 1.0100x over previous
//
#include <hip/hip_runtime.h>
#include <stdint.h>

// MS-SSIM + L1 fused loss, MI355X.
// R11: hoist WM weight fragments into registers. R10 counters showed the
// LDS pipe as the bottleneck (~41us of 77us), and 46% of conv LDS traffic
// was re-reading the SAME wave-invariant WM fragments every plane (H B-frag
// and V A-frag share per-lane addressing WM[(t*16+l16)*SSTR+quad*8+32c]).
// Load 6 bf16x8 frags once per build_wm (~24 VGPR; LDS is the occupancy
// binder so up to 256 VGPR is free), reuse across planes and across
// same-sigma conv passes. Everything else is R10 (verified).

#define TILE 32
#define HALO 16
#define SSTR 72            // bf16 stride (144B row, 16B-multiple)
#define PLN  (64 * SSTR)
#define PTPLN (32 * SSTR)
#define NT   256

#define C1c 1.0e-4f
#define C2c 9.0e-4f

typedef short bf16x8 __attribute__((ext_vector_type(8)));
typedef float f32x4  __attribute__((ext_vector_type(4)));
typedef unsigned short ush;

// ---- compile-time 1/sum of the 33-tap gaussian ----
constexpr double cexp(double xx) {
  if (xx < -700.0) return 0.0;
  const double ln2 = 0.6931471805599453, il2 = 1.4426950408889634;
  double kd = xx * il2;
  long long k = (long long)(kd + (kd >= 0 ? 0.5 : -0.5));
  double r = xx - (double)k * ln2;
  double t = 1.0, s = 1.0;
  for (int i = 1; i <= 22; ++i) { t *= r / (double)i; s += t; }
  double p = 1.0, base = (k >= 0) ? 2.0 : 0.5;
  long long n = (k >= 0) ? k : -k;
  while (n) { if (n & 1) p *= base; base *= base; n >>= 1; }
  return s * p;
}
constexpr float gsi(double sigma) {
  double inv = 1.0 / (2.0 * sigma * sigma);
  double s = 0.0;
  for (int k = -16; k <= 16; ++k) s += cexp(-(double)(k * k) * inv);
  return (float)(1.0 / s);
}
constexpr float SI05 = gsi(0.5), SI10 = gsi(1.0), SI20 = gsi(2.0),
                SI40 = gsi(4.0), SI80 = gsi(8.0);

// pack two f32 -> bf16x2 (round-half-up)
__device__ __forceinline__ unsigned f2bf_pk(float lo, float hi) {
  union { float f; unsigned u; } a, b; a.f = lo; b.f = hi;
  return __builtin_amdgcn_perm(b.u + 0x8000u, a.u + 0x8000u, 0x07060302u);
}
__device__ __forceinline__ ush f2bf1(float f) {
  union { float f; unsigned u; } c; c.f = f;
  return (ush)((c.u + 0x8000u) >> 16);
}

struct WFrag {
  bf16x8 h[2][2];   // [nt][kchunk] : H-pass B-operand
  bf16x8 v[2];      // [kchunk]     : V-pass A-operand (t = wave>>1 baked in)
};

// Fill WM[m][k] = wf5[SIG][k-m] (k-m in [0,32] else 0), then load frags.
template<int SIG>
__device__ __forceinline__ void build_wm(ush* __restrict__ WM,
                                         const float (*__restrict__ wf5)[40],
                                         int tid, int wave, int lane,
                                         WFrag& W) {
  __syncthreads();                 // prior WM/frag readers + staged XQ ordered
  #pragma unroll
  for (int i = 0; i < 8; ++i) {
    const int idx = i * 256 + tid;         // 0..2047
    const int m = idx >> 6, k = idx & 63;
    const int t = k - m;
    const int tc = t < 0 ? 0 : (t > 32 ? 32 : t);
    float v = wf5[SIG][tc];
    v = (t >= 0 && t <= 32) ? v : 0.f;
    WM[m * SSTR + k] = f2bf1(v);
  }
  __syncthreads();                 // WM ready
  const int l16 = lane & 15, quad = lane >> 4;
  #pragma unroll
  for (int t = 0; t < 2; ++t)
    #pragma unroll
    for (int c = 0; c < 2; ++c)
      W.h[t][c] = *(const bf16x8*)(WM + (t * 16 + l16) * SSTR + quad * 8 + 32 * c);
  const int sv0 = (wave >> 1) * 16;
  W.v[0] = *(const bf16x8*)(WM + (sv0 + l16) * SSTR + quad * 8);
  W.v[1] = *(const bf16x8*)(WM + (sv0 + l16) * SSTR + quad * 8 + 32);
}

// One separable conv pass via two banded GEMMs; weights from registers.
// Caller must ensure a barrier ordered XQ (stores) / PT (prior readers).
template<int NQ>
__device__ __forceinline__ void conv_pass(const ush* __restrict__ XQ, int q0,
                                          const WFrag& W,
                                          ush* __restrict__ PT,
                                          int wave, int lane, f32x4* V) {
  const int l16 = lane & 15, quad = lane >> 4;
  const int m0 = wave * 16;
  // H-GEMM: D(64x32) = XQ(64x64) x Wh; store transposed bf16 into PT
  #pragma unroll
  for (int q = 0; q < NQ; ++q) {
    const ush* xp = XQ + (q0 + q) * PLN + (m0 + l16) * SSTR + quad * 8;
    const bf16x8 a0 = *(const bf16x8*)xp;
    const bf16x8 a1 = *(const bf16x8*)(xp + 32);
    #pragma unroll
    for (int nt = 0; nt < 2; ++nt) {
      f32x4 acc = {0.f, 0.f, 0.f, 0.f};
      acc = __builtin_amdgcn_mfma_f32_16x16x32_bf16(a0, W.h[nt][0], acc, 0, 0, 0);
      acc = __builtin_amdgcn_mfma_f32_16x16x32_bf16(a1, W.h[nt][1], acc, 0, 0, 0);
      uint2 u;
      u.x = f2bf_pk(acc[0], acc[1]);
      u.y = f2bf_pk(acc[2], acc[3]);
      *(uint2*)(PT + q * PTPLN + (nt * 16 + l16) * SSTR + m0 + quad * 4) = u;
    }
  }
  __syncthreads();                 // PT complete
  // V-GEMM: D(32x32) = Wv(32x64) x P
  const int n0 = (wave & 1) * 16;
  #pragma unroll
  for (int q = 0; q < NQ; ++q) {
    const ush* pp = PT + q * PTPLN + (n0 + l16) * SSTR + quad * 8;
    const bf16x8 b0 = *(const bf16x8*)pp;
    const bf16x8 b1 = *(const bf16x8*)(pp + 32);
    f32x4 acc = {0.f, 0.f, 0.f, 0.f};
    acc = __builtin_amdgcn_mfma_f32_16x16x32_bf16(W.v[0], b0, acc, 0, 0, 0);
    acc = __builtin_amdgcn_mfma_f32_16x16x32_bf16(W.v[1], b1, acc, 0, 0, 0);
    V[q] = acc;
  }
}

// SSIM epilogue on V[5]
__device__ __forceinline__ void ssim_fold(const f32x4* V, int mult, bool last,
                                          float* PIcs) {
  #pragma unroll
  for (int r = 0; r < 4; ++r) {
    const float mux = V[0][r], muy = V[1][r];
    const float A = mux * muy;
    const float Bq = mux * mux + muy * muy;
    const float S = V[2][r] + V[3][r] - Bq;
    const float sxy = V[4][r] - A;
    const float cs = (2.f * sxy + C2c) * __builtin_amdgcn_rcpf(S + C2c);
    float p = cs;
    if (mult >= 2) p *= cs;
    if (mult >= 3) p *= cs;
    if (last) {
      const float l = (2.f * A + C1c) * __builtin_amdgcn_rcpf(Bq + C1c);
      p *= l * l * l;
    }
    PIcs[r] *= p;
  }
}

__global__ __launch_bounds__(NT)
void msssim_fused_kernel(const float* __restrict__ x, const float* __restrict__ y,
                         const float* __restrict__ disc,
                         float* __restrict__ partials) {
  __shared__ ush XQ[5 * PLN];      // planes: x, y, x2, y2, xy (plane4 -> SAD at end)
  __shared__ ush PT[5 * PTPLN];
  __shared__ ush WM[32 * SSTR];
  __shared__ float wf5[5][40];
  __shared__ float red[12];

  const int tid = threadIdx.x;
  const int wave = tid >> 6, lane = tid & 63;
  const int bx = blockIdx.x, by = blockIdx.y, b = blockIdx.z;
  const int x0 = bx * TILE - HALO, y0 = by * TILE - HALO;
  const int blk = (b * 16 + by) * 16 + bx;

  // disc^2 partial (16 elems/block), issued early so latency hides
  float d2 = 0.f;
  { const int di = blk * 16 + tid;
    if (tid < 16 && di < 8 * 62 * 62) { const float dd = disc[di] - 1.f; d2 = dd * dd; } }

  // one-time tap tables (first build_wm's leading barrier orders readers)
  if (tid < 165) {
    const int sig = tid / 33;
    const int k = tid - sig * 33;
    const float d = (float)(k - 16);
    float inv, si;
    if (sig == 0)      { inv = 2.0f;       si = SI05; }
    else if (sig == 1) { inv = 0.5f;       si = SI10; }
    else if (sig == 2) { inv = 0.125f;     si = SI20; }
    else if (sig == 3) { inv = 0.03125f;   si = SI40; }
    else               { inv = 0.0078125f; si = SI80; }
    wf5[sig][k] = __expf(-d * d * inv) * si;
  }

  const int sr = tid >> 4;           // staging row within 16-row band
  const int sc = (tid & 15) * 4;     // staging col group

  float4 PX[4], PY[4];
  auto issue_loads = [&](int ch) {
    const float* __restrict__ xs = x + (size_t)(b * 3 + ch) * 262144;
    const float* __restrict__ ys = y + (size_t)(b * 3 + ch) * 262144;
    #pragma unroll
    for (int it = 0; it < 4; ++it) {
      const int r = it * 16 + sr;
      const int gy = y0 + r, gx = x0 + sc;
      const bool rowok = (gy >= 0) && (gy < 512);
      if (rowok && gx >= 0 && gx <= 508) {
        PX[it] = *(const float4*)(xs + gy * 512 + gx);
        PY[it] = *(const float4*)(ys + gy * 512 + gx);
      } else {
        float tx[4], ty[4];
        #pragma unroll
        for (int e = 0; e < 4; ++e) {
          const int g = gx + e;
          const bool ok = rowok && (g >= 0) && (g < 512);
          tx[e] = ok ? xs[gy * 512 + g] : 0.f;
          ty[e] = ok ? ys[gy * 512 + g] : 0.f;
        }
        PX[it] = make_float4(tx[0], tx[1], tx[2], tx[3]);
        PY[it] = make_float4(ty[0], ty[1], ty[2], ty[3]);
      }
    }
  };

  float PIcs[4] = {1.f, 1.f, 1.f, 1.f};
  float sad[4][4];                    // sum over channels of |x-y|, 16 px/thread
  #pragma unroll
  for (int it = 0; it < 4; ++it)
    #pragma unroll
    for (int e = 0; e < 4; ++e) sad[it][e] = 0.f;

  issue_loads(0);

  // ---- staging helper: 5 planes + SAD accumulation ----
  auto stage = [&]() {
    #pragma unroll
    for (int it = 0; it < 4; ++it) {
      const int r = it * 16 + sr;
      float xv[4] = {PX[it].x, PX[it].y, PX[it].z, PX[it].w};
      float yv[4] = {PY[it].x, PY[it].y, PY[it].z, PY[it].w};
      float q2[4], q3[4], q4[4];
      #pragma unroll
      for (int e = 0; e < 4; ++e) {
        xv[e] = fmaf(xv[e], 0.5f, 0.5f);
        yv[e] = fmaf(yv[e], 0.5f, 0.5f);
        q2[e] = xv[e] * xv[e]; q3[e] = yv[e] * yv[e];
        q4[e] = xv[e] * yv[e];
        sad[it][e] += fabsf(xv[e] - yv[e]);
      }
      const int off = r * SSTR + sc;
      *(uint2*)(XQ + 0 * PLN + off) = make_uint2(f2bf_pk(xv[0], xv[1]), f2bf_pk(xv[2], xv[3]));
      *(uint2*)(XQ + 1 * PLN + off) = make_uint2(f2bf_pk(yv[0], yv[1]), f2bf_pk(yv[2], yv[3]));
      *(uint2*)(XQ + 2 * PLN + off) = make_uint2(f2bf_pk(q2[0], q2[1]), f2bf_pk(q2[2], q2[3]));
      *(uint2*)(XQ + 3 * PLN + off) = make_uint2(f2bf_pk(q3[0], q3[1]), f2bf_pk(q3[2], q3[3]));
      *(uint2*)(XQ + 4 * PLN + off) = make_uint2(f2bf_pk(q4[0], q4[1]), f2bf_pk(q4[2], q4[3]));
    }
  };

  f32x4 V[5];
  WFrag W;

  // ======== ch0: sigma 0.5 (x3), sigma 1 (x2) ========
  stage();
  issue_loads(1);
  build_wm<0>(WM, wf5, tid, wave, lane, W);     // leading barrier orders XQ too
  conv_pass<5>(XQ, 0, W, PT, wave, lane, V);
  ssim_fold(V, 3, false, PIcs);
  build_wm<1>(WM, wf5, tid, wave, lane, W);
  conv_pass<5>(XQ, 0, W, PT, wave, lane, V);
  ssim_fold(V, 2, false, PIcs);

  // ======== ch1: sigma 1 (x1, frags reused), sigma 2 (x3), sigma 4 (x1) ======
  stage();
  issue_loads(2);
  __syncthreads();                              // XQ staged (frags unchanged)
  conv_pass<5>(XQ, 0, W, PT, wave, lane, V);
  ssim_fold(V, 1, false, PIcs);
  build_wm<2>(WM, wf5, tid, wave, lane, W);
  conv_pass<5>(XQ, 0, W, PT, wave, lane, V);
  ssim_fold(V, 3, false, PIcs);
  build_wm<3>(WM, wf5, tid, wave, lane, W);
  conv_pass<5>(XQ, 0, W, PT, wave, lane, V);
  ssim_fold(V, 1, false, PIcs);

  // ======== ch2: sigma 4 (x2, frags reused), sigma 8 (x3 + l^3) ========
  stage();
  __syncthreads();                              // XQ staged (frags unchanged)
  conv_pass<5>(XQ, 0, W, PT, wave, lane, V);
  ssim_fold(V, 2, false, PIcs);
  build_wm<4>(WM, wf5, tid, wave, lane, W);
  conv_pass<5>(XQ, 0, W, PT, wave, lane, V);
  ssim_fold(V, 3, true, PIcs);

  // ======== deferred gaussian L1: conv(SAD, sigma 8) (frags reused) ========
  #pragma unroll
  for (int it = 0; it < 4; ++it) {
    const int off = (it * 16 + sr) * SSTR + sc;
    *(uint2*)(XQ + 4 * PLN + off) =
        make_uint2(f2bf_pk(sad[it][0], sad[it][1]), f2bf_pk(sad[it][2], sad[it][3]));
  }
  __syncthreads();                              // SAD plane staged
  f32x4 V1[1];
  conv_pass<1>(XQ, 4, W, PT, wave, lane, V1);

  // absacc = central sum of SAD regs (rows 16..47 are it=1,2; cols via sc)
  float absacc = 0.f;
  if (sc >= 16 && sc < 48) {
    #pragma unroll
    for (int it = 1; it <= 2; ++it)
      #pragma unroll
      for (int e = 0; e < 4; ++e) absacc += sad[it][e];
  }

  float mixsum = 0.f;
  #pragma unroll
  for (int r = 0; r < 4; ++r) {
    const float ssim = 1.f - PIcs[r];
    mixsum += 200.f * (0.025f * ssim + 0.975f * (V1[0][r] * (1.f / 3.f)));
  }

  #pragma unroll
  for (int off = 32; off > 0; off >>= 1) {
    mixsum += __shfl_down(mixsum, off);
    absacc += __shfl_down(absacc, off);
    d2     += __shfl_down(d2, off);
  }
  if (lane == 0) { red[wave] = mixsum; red[4 + wave] = absacc; red[8 + wave] = d2; }
  __syncthreads();
  if (tid == 0) {
    float m = 0.f, a = 0.f, d = 0.f;
    #pragma unroll
    for (int i = 0; i < 4; ++i) { m += red[i]; a += red[4 + i]; d += red[8 + i]; }
    partials[3 * blk + 0] = m;
    partials[3 * blk + 1] = a;
    partials[3 * blk + 2] = d;
  }
}

__global__ __launch_bounds__(512)
void msssim_final_kernel(const float* __restrict__ partials,
                         float* __restrict__ out) {
  __shared__ float red[24];
  const int tid = threadIdx.x;
  float m = 0.f, a = 0.f, d2 = 0.f;
  for (int j = tid; j < 2048; j += 512) {
    m  += partials[3 * j + 0];
    a  += partials[3 * j + 1];
    d2 += partials[3 * j + 2];
  }
  #pragma unroll
  for (int off = 32; off > 0; off >>= 1) {
    m  += __shfl_down(m, off);
    a  += __shfl_down(a, off);
    d2 += __shfl_down(d2, off);
  }
  const int wave = tid >> 6, lane = tid & 63;
  if (lane == 0) { red[wave] = m; red[8 + wave] = a; red[16 + wave] = d2; }
  __syncthreads();
  if (tid == 0) {
    float sm = 0.f, sa = 0.f, sd = 0.f;
    #pragma unroll
    for (int i = 0; i < 8; ++i) { sm += red[i]; sa += red[8 + i]; sd += red[16 + i]; }
    const float mix_mean  = sm / (8.f * 512.f * 512.f);
    const float abs_mean  = sa / (8.f * 3.f * 512.f * 512.f);
    const float disc_mean = sd / (8.f * 62.f * 62.f);
    out[0] = 0.5f * (mix_mean + 100.f * abs_mean + disc_mean);
  }
}

extern "C" void kernel_launch(void* const* d_in, const int* in_sizes, int n_in,
                              void* d_out, int out_size, void* d_ws, size_t ws_size,
                              hipStream_t stream) {
  const float* x    = (const float*)d_in[0];
  const float* y    = (const float*)d_in[1];
  const float* disc = (const float*)d_in[2];
  // d_in[3] = g_masks (unused: weights recomputed on device)
  float* partials = (float*)d_ws;   // 2048*3 floats, fully overwritten each call
  dim3 grid(16, 16, 8);
  msssim_fused_kernel<<<grid, NT, 0, stream>>>(x, y, disc, partials);
  msssim_final_kernel<<<1, 512, 0, stream>>>(partials, (float*)d_out);
}